// Round 4
// baseline (73.460 us; speedup 1.0000x reference)
//
#include <hip/hip_runtime.h>
#include <hip/hip_bf16.h>

#define M_DIM 8192
#define N_DIM 8192

typedef short short8 __attribute__((ext_vector_type(8)));
typedef float f32x4 __attribute__((ext_vector_type(4)));

static __device__ __forceinline__ short f2bf(float f) {
    __hip_bfloat16 h = __float2bfloat16(f);   // RNE convert
    union { __hip_bfloat16 h; short s; } u;
    u.h = h;
    return u.s;
}

// Kernel 1: activation [64, 8192] f32 -> actT [8192, 64] bf16 (transposed, packed)
__global__ __launch_bounds__(256) void transpose_act(const float* __restrict__ act,
                                                     short* __restrict__ actT) {
    __shared__ float tile[64][65];   // +1 pad: conflict-free column reads
    const int n0 = blockIdx.x * 64;
    const int tid = threadIdx.x;
    #pragma unroll
    for (int i = tid; i < 64 * 64; i += 256) {
        int k = i >> 6, n = i & 63;
        tile[k][n] = act[k * N_DIM + n0 + n];     // coalesced row reads
    }
    __syncthreads();
    #pragma unroll
    for (int i = tid; i < 64 * 64; i += 256) {
        int n = i >> 6, k = i & 63;
        actT[(n0 + n) * 64 + k] = f2bf(tile[k][n]);  // coalesced bf16 writes
    }
}

// Kernel 2: C[m,n] = dq[m,:] @ act[:,n].  Tile 64x512, 4 waves split N (disjoint
// 128-col slices). Full tile accumulated in registers (128 VGPR acc), then a
// two-pass block-level LDS epilogue streams rows as 1KB-contiguous float4 stores
// (2KB per row) for DRAM-friendly write bursts.
__global__ __launch_bounds__(256, 2) void gemm_dq(const float* __restrict__ scale,
                                                  const int* __restrict__ offset,
                                                  const int* __restrict__ weight,
                                                  const short* __restrict__ actT,
                                                  float* __restrict__ C) {
    __shared__ float epi[32 * 512];   // 64 KB: 32 rows x 512 cols, XOR-swizzled

    const int tid  = threadIdx.x;
    const int lane = tid & 63;
    const int wid  = tid >> 6;
    const int l15  = lane & 15;
    const int l4   = lane >> 4;

    const int bm = (int)blockIdx.x >> 4;       // 16 consecutive blocks share bm:
    const int bn = (int)blockIdx.x & 15;       // concurrent blocks write contiguous N
    const int m0 = bm * 64;
    const int n0 = bn * 512;

    // ---- A fragments: dequantize 4-bit weights directly into registers.
    // Lane holds row m = m0+fm*16+(lane&15), k = kh*32+(lane>>4)*8+j
    // => group g = kh*4+(lane>>4): one weight word, one scale, one offset nibble.
    short8 afrag[2][4];
    #pragma unroll
    for (int kh = 0; kh < 2; ++kh) {
        const int g = kh * 4 + l4;
        #pragma unroll
        for (int fm = 0; fm < 4; ++fm) {
            const int m = m0 + fm * 16 + l15;
            const unsigned w = (unsigned)weight[m * 8 + g];
            const float   s = scale[m * 8 + g];
            const int   off = (int)(((unsigned)offset[m] >> (4 * g)) & 15u);
            short8 a;
            #pragma unroll
            for (int j = 0; j < 8; ++j) {
                const int wv = (int)((w >> (4 * j)) & 15u);
                a[j] = f2bf(s * (float)(wv - off));
            }
            afrag[kh][fm] = a;
        }
    }

    // ---- MFMA: wave owns 64 rows x 128 cols (8 fn-fragments), B loads disjoint per wave.
    f32x4 acc[4][8] = {};
    #pragma unroll
    for (int fn = 0; fn < 8; ++fn) {
        const short* bp = actT + (size_t)(n0 + wid * 128 + fn * 16 + l15) * 64 + l4 * 8;
        const short8 b0 = *reinterpret_cast<const short8*>(bp);
        const short8 b1 = *reinterpret_cast<const short8*>(bp + 32);
        #pragma unroll
        for (int fm = 0; fm < 4; ++fm) {
            acc[fm][fn] = __builtin_amdgcn_mfma_f32_16x16x32_bf16(
                afrag[0][fm], b0, acc[fm][fn], 0, 0, 0);
            acc[fm][fn] = __builtin_amdgcn_mfma_f32_16x16x32_bf16(
                afrag[1][fm], b1, acc[fm][fn], 0, 0, 0);
        }
    }

    // ---- Epilogue: two passes of 32 rows. Stage into swizzled LDS, then all
    // waves cooperatively stream full rows: each store instr = 1KB contiguous.
    #pragma unroll
    for (int pass = 0; pass < 2; ++pass) {
        if (pass) __syncthreads();   // pass-0 reads done before overwrite
        #pragma unroll
        for (int f = 0; f < 2; ++f) {
            const int fm = pass * 2 + f;
            #pragma unroll
            for (int fn = 0; fn < 8; ++fn) {
                const int col = wid * 128 + fn * 16 + l15;
                #pragma unroll
                for (int j = 0; j < 4; ++j) {
                    const int row = f * 16 + l4 * 4 + j;
                    epi[row * 512 + (col ^ ((row & 7) * 4))] = acc[fm][fn][j];
                }
            }
        }
        __syncthreads();
        #pragma unroll
        for (int s = 0; s < 16; ++s) {
            const int row = wid * 8 + (s >> 1);            // wave streams 8 rows
            const int c4  = (s & 1) * 256 + lane * 4;      // half-row = 1KB contiguous
            const f32x4 v = *reinterpret_cast<const f32x4*>(
                &epi[row * 512 + (c4 ^ ((row & 7) * 4))]);
            *reinterpret_cast<f32x4*>(
                &C[(size_t)(m0 + pass * 32 + row) * N_DIM + n0 + c4]) = v;
        }
    }
}

extern "C" void kernel_launch(void* const* d_in, const int* in_sizes, int n_in,
                              void* d_out, int out_size, void* d_ws, size_t ws_size,
                              hipStream_t stream) {
    const float* scale  = (const float*)d_in[0];
    const int*   offset = (const int*)d_in[1];
    const int*   weight = (const int*)d_in[2];
    const float* act    = (const float*)d_in[3];
    float* out  = (float*)d_out;
    short* actT = (short*)d_ws;   // 8192*64*2 = 1 MB scratch

    transpose_act<<<N_DIM / 64, 256, 0, stream>>>(act, actT);

    const int grid = (M_DIM / 64) * (N_DIM / 512);   // 2048 blocks
    gemm_dq<<<grid, 256, 0, stream>>>(scale, offset, weight, actT, out);
}